// Round 7
// baseline (954.076 us; speedup 1.0000x reference)
//
#include <hip/hip_runtime.h>
#include <cstdint>
#include <cstddef>

// Problem constants (fixed by the reference: B=8, S=1024, H=512, 8 speakers, 2 layers)
#define SS 1024
#define HH 512
#define G3 1536  // 3*H

typedef _Float16 half8 __attribute__((ext_vector_type(8)));
typedef float f32x4 __attribute__((ext_vector_type(4)));
typedef unsigned u32x4 __attribute__((ext_vector_type(4)));

// ---- workspace layout (bytes) ----
// Rings are PURE f16 (no tags). Synchronization via per-producer-wave flags:
// producer stores data, drains (vmcnt(0) = acked at coherence point), then
// stores its flag. Flag visible => data visible. memset(0) = "0 rounds done".
static constexpr unsigned OFF_TLIST = 0;                 // [8][8][1024] int
static constexpr unsigned OFF_LEN   = 262144;            // [64] int
static constexpr unsigned OFF_META  = 262400;            // [8] int per-speaker max len
static constexpr unsigned OFF_H0    = 262656;            // ushort[8][64][512] = 512KB
static constexpr unsigned OFF_H1    = OFF_H0 + 524288;   // ushort[8][64][512] = 512KB
static constexpr unsigned OFF_FLG   = OFF_H1 + 524288;   // u32[2][8][64] = 4KB
static constexpr unsigned WS_NEED   = OFF_FLG + 4096;

__device__ __forceinline__ half8 cvt8(const float* p) {
  float4 u = *(const float4*)p;
  float4 v = *(const float4*)(p + 4);
  half8 h;
  h[0]=(_Float16)u.x; h[1]=(_Float16)u.y; h[2]=(_Float16)u.z; h[3]=(_Float16)u.w;
  h[4]=(_Float16)v.x; h[5]=(_Float16)v.y; h[6]=(_Float16)v.z; h[7]=(_Float16)v.w;
  return h;
}

__device__ __forceinline__ float sigm(float x) { return 1.f / (1.f + __expf(-x)); }

// ---- flag polls (tiny footprint: 64 contiguous words per flag vector) ----
__device__ __forceinline__ void poll1(const unsigned* f, unsigned tgt) {
  const int l = threadIdx.x & 63;
  unsigned it = 0;
  for (;;) {
    unsigned v = __hip_atomic_load(f + l, __ATOMIC_RELAXED, __HIP_MEMORY_SCOPE_AGENT);
    if (__all((int)(v >= tgt))) break;
    __builtin_amdgcn_s_sleep(1);
    if (++it > 3000000u) break;   // safety
  }
}
__device__ __forceinline__ void poll2(const unsigned* f0, const unsigned* f1, unsigned tgt) {
  const int l = threadIdx.x & 63;
  unsigned it = 0;
  for (;;) {
    unsigned v0 = __hip_atomic_load(f0 + l, __ATOMIC_RELAXED, __HIP_MEMORY_SCOPE_AGENT);
    unsigned v1 = __hip_atomic_load(f1 + l, __ATOMIC_RELAXED, __HIP_MEMORY_SCOPE_AGENT);
    if (__all((int)(v0 >= tgt && v1 >= tgt))) break;
    __builtin_amdgcn_s_sleep(1);
    if (++it > 3000000u) break;   // safety
  }
}
// poll until min(f[]) >= tgt, return the actual wave-min (for lazy re-checks)
__device__ __forceinline__ unsigned pollmin(const unsigned* f, unsigned tgt) {
  const int l = threadIdx.x & 63;
  unsigned v, it = 0;
  for (;;) {
    v = __hip_atomic_load(f + l, __ATOMIC_RELAXED, __HIP_MEMORY_SCOPE_AGENT);
    if (__all((int)(v >= tgt))) break;
    __builtin_amdgcn_s_sleep(1);
    if (++it > 3000000u) break;   // safety
  }
#pragma unroll
  for (int d = 1; d < 64; d <<= 1) {
    unsigned o = (unsigned)__shfl_xor((int)v, d, 64);
    v = (o < v) ? o : v;
  }
  return v;
}

// ---- one-shot UC bulk loads (sc0 sc1 -> coherence point), issued ONCE per round ----
__device__ __forceinline__ void uc_ld2(const unsigned* p, u32x4& a, u32x4& b) {
  asm volatile(
    "global_load_dwordx4 %0, %2, off sc0 sc1\n\t"
    "global_load_dwordx4 %1, %2, off offset:16 sc0 sc1\n\t"
    "s_waitcnt vmcnt(0)"
    : "=&v"(a), "=&v"(b) : "v"(p) : "memory");
  __builtin_amdgcn_sched_barrier(0);
}
__device__ __forceinline__ void uc_ld4(const unsigned* p, const unsigned* q,
                                       u32x4& a, u32x4& b, u32x4& c, u32x4& d) {
  asm volatile(
    "global_load_dwordx4 %0, %4, off sc0 sc1\n\t"
    "global_load_dwordx4 %1, %4, off offset:16 sc0 sc1\n\t"
    "global_load_dwordx4 %2, %5, off sc0 sc1\n\t"
    "global_load_dwordx4 %3, %5, off offset:16 sc0 sc1\n\t"
    "s_waitcnt vmcnt(0)"
    : "=&v"(a), "=&v"(b), "=&v"(c), "=&v"(d) : "v"(p), "v"(q) : "memory");
  __builtin_amdgcn_sched_barrier(0);
}

__device__ __forceinline__ void uc_st32(unsigned* p, unsigned v) {
  __hip_atomic_store(p, v, __ATOMIC_RELAXED, __HIP_MEMORY_SCOPE_AGENT);
}

// ---------------- prep: build per-(sp,b) timestep lists ----------------
__global__ void prep_kernel(const int* __restrict__ spk, int* __restrict__ tlist,
                            int* __restrict__ len, int* __restrict__ meta) {
  __shared__ int slen[64];
  const int t = threadIdx.x;   // 0..63
  const int sp = t >> 3, b = t & 7;
  int cnt = 0;
  int* tl = tlist + (sp * 8 + b) * SS;
  const int4* srow = (const int4*)(spk + b * SS);
#pragma unroll 4
  for (int i = 0; i < SS / 4; ++i) {
    int4 v = srow[i];
    if (v.x == sp) tl[cnt++] = 4 * i + 0;
    if (v.y == sp) tl[cnt++] = 4 * i + 1;
    if (v.z == sp) tl[cnt++] = 4 * i + 2;
    if (v.w == sp) tl[cnt++] = 4 * i + 3;
  }
  len[t] = cnt;
  slen[t] = cnt;
  for (int i = cnt; i < SS; ++i) tl[i] = 0;  // pad so speculative reads are safe
  __syncthreads();
  if (t < 8) {
    int m = 0;
    for (int i = 0; i < 8; ++i) m = max(m, slen[t * 8 + i]);
    meta[t] = m;
  }
}

// ---------------- persistent GRU kernel, layer-split, flag-gated ----------------
// 256 WGs: L = wg&1, sp = (wg>>1)&7, og = wg>>4. WG owns 32 outputs of one layer.
// Per round: poll 64-word flag vector(s) (tiny) -> ONE bulk UC load of the h
// slice(s) -> LDS stage -> MFMA -> gates -> publish f16 pairs -> per-wave
// vmcnt(0) drain -> per-wave flag store. 8-slot rings; L0 lazily back-pressures
// on the L1 flag vector (L1 must pass round r-7 before slot r&7 is overwritten).
__launch_bounds__(256, 1)
__global__ void gru_main(const float* __restrict__ x,
                         const float* __restrict__ Wi, const float* __restrict__ Wh,
                         const float* __restrict__ bi, const float* __restrict__ bh,
                         const int* __restrict__ tlist, const int* __restrict__ len,
                         const int* __restrict__ meta,
                         unsigned short* __restrict__ h0ring,
                         unsigned short* __restrict__ h1ring,
                         unsigned* __restrict__ flg, float* __restrict__ out) {
  const int wg = blockIdx.x;       // 0..255
  const int L  = wg & 1;
  const int sp = (wg >> 1) & 7;
  const int og = wg >> 4;          // 0..15
  const int j0 = og * 32;
  const int tid = threadIdx.x;
  const int w  = tid >> 6;         // wave 0..3
  const int kw = w & 1;            // K half
  const int nw = w >> 1;           // N half (tiles 3*nw..3*nw+2)
  const int l  = tid & 63;
  const int lr = l & 15;           // A-row (batch) / B-col (weight row in tile)
  const int lg = l >> 4;           // k sub-group
  const int b8 = lr & 7;           // batch row (rows 8-15 duplicate 0-7)

  __shared__ _Float16 hstA[8][544];       // staged h0 (pitch 1088B: frag reads bank-injective)
  __shared__ _Float16 hstB[8][544];       // staged h1 (layer1)
  __shared__ float accW[6][2][320];       // Wh·h partials [tile][kw][n*20+m]
  __shared__ float accX2[2][6][2][320];   // L0: x-GEMM dbuf; L1: [0] = Wi1·h0

  unsigned* flg0 = flg + (0 * 8 + sp) * 64;
  unsigned* flg1 = flg + (1 * 8 + sp) * 64;

  // ---- weight preload: fp32 global -> f16 register fragments (done once) ----
  const size_t WMAT = (size_t)G3 * HH;
  const float* pWi = Wi + (size_t)(sp * 2 + L) * WMAT;
  const float* pWh = Wh + (size_t)(sp * 2 + L) * WMAT;
  half8 bwX[3][8], bwH[3][8];   // 96 rows (3 gates x 32 outs), this wave's 3 tiles, K-half
#pragma unroll
  for (int t = 0; t < 3; ++t) {
    const int T6 = 3 * nw + t;
    const int rr = T6 * 16 + lr;
    const size_t row = (size_t)((rr >> 5) * HH + j0 + (rr & 31));
#pragma unroll
    for (int q = 0; q < 8; ++q) {
      const int k0 = lg * 8 + (kw * 8 + q) * 32;
      bwX[t][q] = cvt8(pWi + row * HH + k0);
      bwH[t][q] = cvt8(pWh + row * HH + k0);
    }
  }

  // ---- gate-thread metadata: all 256 threads -> (batch gb, output gj) ----
  const int gb = tid >> 5;      // 0..7  (wave w holds gb = 2w, 2w+1)
  const int gj = tid & 31;      // 0..31
  const int Lb = len[sp * 8 + gb];
  const int* tlB = tlist + (sp * 8 + gb) * SS;
  float bgi[3], bgh[3];
#pragma unroll
  for (int g = 0; g < 3; ++g) {
    bgi[g] = bi[(sp * 2 + L) * G3 + g * HH + j0 + gj];
    bgh[g] = bh[(sp * 2 + L) * G3 + g * HH + j0 + gj];
  }

  // per-lane x-gather metadata (layer0 only; A row b8 supplies batch b8)
  const int* tlX = tlist + (sp * 8 + b8) * SS;
  const float* xrow = x + (size_t)b8 * SS * HH;

  const int R = meta[sp];
  const int stg_c = tid >> 5;            // staged chain row
  const int stg_o = (tid & 31) * 16;     // staged f16 col base (32B/thread)

  float hprev = 0.f;

  if (L == 0) {
    // ================= LAYER 0 (critical self-loop) =================
    int lastmin = 0;
    // prologue: x-GEMM (Wi0*x_0) into accX2[0]
    {
      const int tx = tlX[0];
      const float* xs = xrow + (size_t)tx * HH;
      half8 xf[8];
      f32x4 a0, a1, a2;
#pragma unroll
      for (int e = 0; e < 4; ++e) { a0[e] = 0.f; a1[e] = 0.f; a2[e] = 0.f; }
#pragma unroll
      for (int q = 0; q < 8; ++q) xf[q] = cvt8(xs + lg * 8 + (kw * 8 + q) * 32);
#pragma unroll
      for (int q = 0; q < 8; ++q) {
        a0 = __builtin_amdgcn_mfma_f32_16x16x32_f16(xf[q], bwX[0][q], a0, 0, 0, 0);
        a1 = __builtin_amdgcn_mfma_f32_16x16x32_f16(xf[q], bwX[1][q], a1, 0, 0, 0);
        a2 = __builtin_amdgcn_mfma_f32_16x16x32_f16(xf[q], bwX[2][q], a2, 0, 0, 0);
      }
      *(f32x4*)&accX2[0][3 * nw + 0][kw][lr * 20 + lg * 4] = a0;
      *(f32x4*)&accX2[0][3 * nw + 1][kw][lr * 20 + lg * 4] = a1;
      *(f32x4*)&accX2[0][3 * nw + 2][kw][lr * 20 + lg * 4] = a2;
    }

    for (int r = 0; r <= R; ++r) {
      // ---- poll peers' flags (data round r-1 visible), then ONE bulk load ----
      if (r > 0) poll1(flg0, (unsigned)r);
      {
        const unsigned* src =
            (const unsigned*)(h0ring + ((size_t)(((r - 1) & 7) * 64 + sp * 8)) * HH) + tid * 8;
        u32x4 a, b;
        uc_ld2(src, a, b);
        *(u32x4*)&hstA[stg_c][stg_o + 0] = a;
        *(u32x4*)&hstA[stg_c][stg_o + 8] = b;
      }
      __syncthreads();

      // ---- A-frags + 24 MFMA (Wh0*h0) ----
      half8 hA[8];
#pragma unroll
      for (int q = 0; q < 8; ++q)
        hA[q] = *(const half8*)&hstA[b8][lg * 8 + (kw * 8 + q) * 32];
      f32x4 c0, c1, c2;
#pragma unroll
      for (int e = 0; e < 4; ++e) { c0[e] = 0.f; c1[e] = 0.f; c2[e] = 0.f; }
#pragma unroll
      for (int q = 0; q < 8; ++q) {
        c0 = __builtin_amdgcn_mfma_f32_16x16x32_f16(hA[q], bwH[0][q], c0, 0, 0, 0);
        c1 = __builtin_amdgcn_mfma_f32_16x16x32_f16(hA[q], bwH[1][q], c1, 0, 0, 0);
        c2 = __builtin_amdgcn_mfma_f32_16x16x32_f16(hA[q], bwH[2][q], c2, 0, 0, 0);
      }
      *(f32x4*)&accW[3 * nw + 0][kw][lr * 20 + lg * 4] = c0;
      *(f32x4*)&accW[3 * nw + 1][kw][lr * 20 + lg * 4] = c1;
      *(f32x4*)&accW[3 * nw + 2][kw][lr * 20 + lg * 4] = c2;
      __syncthreads();

      // ---- gates (pos r, active if r < Lb) ----
      const bool act = (r < Lb);
      if (act) {
        const int xb = r & 1;
        float gi[3], gh[3];
#pragma unroll
        for (int g = 0; g < 3; ++g) {
          const int T6 = 2 * g + (gj >> 4);
          const int idx = (gj & 15) * 20 + gb;
          gi[g] = accX2[xb][T6][0][idx] + accX2[xb][T6][1][idx] + bgi[g];
          gh[g] = accW[T6][0][idx] + accW[T6][1][idx] + bgh[g];
        }
        const float rr_ = sigm(gi[0] + gh[0]);
        const float zz = sigm(gi[1] + gh[1]);
        const float nn = tanhf(gi[2] + rr_ * gh[2]);
        hprev = (1.f - zz) * nn + zz * hprev;
      }

      // ---- lazy back-pressure: L1 must have passed round r-7 before slot r&7
      //      (holding h0_{r-8}) is overwritten; L1 flag >= r-6 <=> round r-7 done ----
      if (lastmin < r - 6) lastmin = (int)pollmin(flg1, (unsigned)(r - 6));

      // ---- publish h0_r (slot r&7) as f16 pairs; drain; per-wave flag ----
      {
        union { _Float16 hf; unsigned short us; } cv; cv.hf = (_Float16)hprev;
        const unsigned hw = (unsigned)cv.us;
        const unsigned up = (unsigned)__shfl_down((int)hw, 1, 64);
        if (act && !(gj & 1)) {
          unsigned* dst = (unsigned*)(h0ring +
              ((size_t)((r & 7) * 64 + sp * 8 + gb)) * HH + j0 + gj);
          uc_st32(dst, (up << 16) | hw);
        }
      }
      asm volatile("s_waitcnt vmcnt(0)" ::: "memory");
      if (l == 0) uc_st32(&flg0[og * 4 + w], (unsigned)(r + 1));

      // ---- shadow x-GEMM (Wi0*x_{r+1}) into accX2[(r+1)&1]; overlaps peers' publish ----
      {
        const int tx = tlX[(r + 1) & (SS - 1)];
        const float* xs = xrow + (size_t)tx * HH;
        half8 xf[8];
        f32x4 a0, a1, a2;
#pragma unroll
        for (int e = 0; e < 4; ++e) { a0[e] = 0.f; a1[e] = 0.f; a2[e] = 0.f; }
#pragma unroll
        for (int q = 0; q < 8; ++q) xf[q] = cvt8(xs + lg * 8 + (kw * 8 + q) * 32);
#pragma unroll
        for (int q = 0; q < 8; ++q) {
          a0 = __builtin_amdgcn_mfma_f32_16x16x32_f16(xf[q], bwX[0][q], a0, 0, 0, 0);
          a1 = __builtin_amdgcn_mfma_f32_16x16x32_f16(xf[q], bwX[1][q], a1, 0, 0, 0);
          a2 = __builtin_amdgcn_mfma_f32_16x16x32_f16(xf[q], bwX[2][q], a2, 0, 0, 0);
        }
        const int db = (r + 1) & 1;
        *(f32x4*)&accX2[db][3 * nw + 0][kw][lr * 20 + lg * 4] = a0;
        *(f32x4*)&accX2[db][3 * nw + 1][kw][lr * 20 + lg * 4] = a1;
        *(f32x4*)&accX2[db][3 * nw + 2][kw][lr * 20 + lg * 4] = a2;
      }
    }
  } else {
    // ================= LAYER 1 (lags L0 by one round) =================
    for (int r = 0; r <= R; ++r) {
      // ---- poll both flag vectors, then ONE bulk load of h0 + h1 slices ----
      if (r > 0) poll2(flg0, flg1, (unsigned)r);
      {
        const unsigned* pa =
            (const unsigned*)(h0ring + ((size_t)(((r - 1) & 7) * 64 + sp * 8)) * HH) + tid * 8;
        const unsigned* pb =
            (const unsigned*)(h1ring + ((size_t)(((r - 2) & 7) * 64 + sp * 8)) * HH) + tid * 8;
        u32x4 a, b, c, d;
        uc_ld4(pa, pb, a, b, c, d);
        *(u32x4*)&hstA[stg_c][stg_o + 0] = a;
        *(u32x4*)&hstA[stg_c][stg_o + 8] = b;
        *(u32x4*)&hstB[stg_c][stg_o + 0] = c;
        *(u32x4*)&hstB[stg_c][stg_o + 8] = d;
      }
      __syncthreads();

      // ---- A-frags + 48 MFMA (Wi1*h0 -> accX2[0], Wh1*h1 -> accW) ----
      half8 hA[8], hB[8];
#pragma unroll
      for (int q = 0; q < 8; ++q) {
        const int k0 = lg * 8 + (kw * 8 + q) * 32;
        hA[q] = *(const half8*)&hstA[b8][k0];
        hB[q] = *(const half8*)&hstB[b8][k0];
      }
      f32x4 cA0, cA1, cA2, cB0, cB1, cB2;
#pragma unroll
      for (int e = 0; e < 4; ++e) {
        cA0[e] = 0.f; cA1[e] = 0.f; cA2[e] = 0.f;
        cB0[e] = 0.f; cB1[e] = 0.f; cB2[e] = 0.f;
      }
#pragma unroll
      for (int q = 0; q < 8; ++q) {
        cA0 = __builtin_amdgcn_mfma_f32_16x16x32_f16(hA[q], bwX[0][q], cA0, 0, 0, 0);
        cA1 = __builtin_amdgcn_mfma_f32_16x16x32_f16(hA[q], bwX[1][q], cA1, 0, 0, 0);
        cA2 = __builtin_amdgcn_mfma_f32_16x16x32_f16(hA[q], bwX[2][q], cA2, 0, 0, 0);
        cB0 = __builtin_amdgcn_mfma_f32_16x16x32_f16(hB[q], bwH[0][q], cB0, 0, 0, 0);
        cB1 = __builtin_amdgcn_mfma_f32_16x16x32_f16(hB[q], bwH[1][q], cB1, 0, 0, 0);
        cB2 = __builtin_amdgcn_mfma_f32_16x16x32_f16(hB[q], bwH[2][q], cB2, 0, 0, 0);
      }
      *(f32x4*)&accX2[0][3 * nw + 0][kw][lr * 20 + lg * 4] = cA0;
      *(f32x4*)&accX2[0][3 * nw + 1][kw][lr * 20 + lg * 4] = cA1;
      *(f32x4*)&accX2[0][3 * nw + 2][kw][lr * 20 + lg * 4] = cA2;
      *(f32x4*)&accW[3 * nw + 0][kw][lr * 20 + lg * 4] = cB0;
      *(f32x4*)&accW[3 * nw + 1][kw][lr * 20 + lg * 4] = cB1;
      *(f32x4*)&accW[3 * nw + 2][kw][lr * 20 + lg * 4] = cB2;
      __syncthreads();

      // ---- gates (pos r-1, active if 1 <= r <= Lb) ----
      const bool act = (r >= 1) && (r <= Lb);
      if (act) {
        float gi[3], gh[3];
#pragma unroll
        for (int g = 0; g < 3; ++g) {
          const int T6 = 2 * g + (gj >> 4);
          const int idx = (gj & 15) * 20 + gb;
          gi[g] = accX2[0][T6][0][idx] + accX2[0][T6][1][idx] + bgi[g];
          gh[g] = accW[T6][0][idx] + accW[T6][1][idx] + bgh[g];
        }
        const float rr_ = sigm(gi[0] + gh[0]);
        const float zz = sigm(gi[1] + gh[1]);
        const float nn = tanhf(gi[2] + rr_ * gh[2]);
        hprev = (1.f - zz) * nn + zz * hprev;
        const int tcur = tlB[(r - 1) & (SS - 1)];
        out[((size_t)(gb * SS + tcur)) * HH + j0 + gj] = hprev;
      }

      // ---- publish h1_{r-1} (slot (r-1)&7) as f16 pairs; drain; per-wave flag ----
      {
        union { _Float16 hf; unsigned short us; } cv; cv.hf = (_Float16)hprev;
        const unsigned hw = (unsigned)cv.us;
        const unsigned up = (unsigned)__shfl_down((int)hw, 1, 64);
        if (act && !(gj & 1)) {
          unsigned* dst = (unsigned*)(h1ring +
              ((size_t)((((r - 1) & 7)) * 64 + sp * 8 + gb)) * HH + j0 + gj);
          uc_st32(dst, (up << 16) | hw);
        }
      }
      asm volatile("s_waitcnt vmcnt(0)" ::: "memory");
      if (l == 0) uc_st32(&flg1[og * 4 + w], (unsigned)(r + 1));
    }
  }
}

extern "C" void kernel_launch(void* const* d_in, const int* in_sizes, int n_in,
                              void* d_out, int out_size, void* d_ws, size_t ws_size,
                              hipStream_t stream) {
  const float* x   = (const float*)d_in[0];
  const int*   spk = (const int*)d_in[1];
  const float* Wi  = (const float*)d_in[2];
  const float* Wh  = (const float*)d_in[3];
  const float* bi  = (const float*)d_in[4];
  const float* bh  = (const float*)d_in[5];
  float* out = (float*)d_out;
  char* ws = (char*)d_ws;

  int*            tlist = (int*)(ws + OFF_TLIST);
  int*            len   = (int*)(ws + OFF_LEN);
  int*            meta  = (int*)(ws + OFF_META);
  unsigned short* h0r   = (unsigned short*)(ws + OFF_H0);
  unsigned short* h1r   = (unsigned short*)(ws + OFF_H1);
  unsigned*       flg   = (unsigned*)(ws + OFF_FLG);

  (void)in_sizes; (void)n_in; (void)out_size; (void)ws_size;

  // zero rings + flags (re-done every launch; graph-capture safe)
  hipMemsetAsync(ws + OFF_H0, 0, WS_NEED - OFF_H0, stream);
  prep_kernel<<<1, 64, 0, stream>>>(spk, tlist, len, meta);
  gru_main<<<256, 256, 0, stream>>>(x, Wi, Wh, bi, bh, tlist, len, meta,
                                    h0r, h1r, flg, out);
}

// Round 8
// 721.387 us; speedup vs baseline: 1.3226x; 1.3226x over previous
//
#include <hip/hip_runtime.h>
#include <cstdint>
#include <cstddef>

// Problem constants (fixed by the reference: B=8, S=1024, H=512, 8 speakers, 2 layers)
#define SS 1024
#define HH 512
#define G3 1536  // 3*H

typedef _Float16 half8 __attribute__((ext_vector_type(8)));
typedef float f32x4 __attribute__((ext_vector_type(4)));
typedef unsigned u32x4 __attribute__((ext_vector_type(4)));

// ---- workspace layout (bytes) ----
// Rings: pure f16. Sync: per-producer-WAVE flags; producer publishes, drains
// (vmcnt(0) = acked at coherence point), then flags. Flag visible => data visible.
static constexpr unsigned OFF_TLIST = 0;                 // [8][8][1024] int
static constexpr unsigned OFF_LEN   = 262144;            // [64] int
static constexpr unsigned OFF_META  = 262400;            // [8] int per-speaker max len
static constexpr unsigned OFF_H0    = 262656;            // u16[8][64][512] = 512KB
static constexpr unsigned OFF_H1    = OFF_H0 + 524288;   // u16[8][64][512] = 512KB
static constexpr unsigned OFF_FLG   = OFF_H1 + 524288;   // u32[2][8][64] = 4KB
static constexpr unsigned WS_NEED   = OFF_FLG + 4096;

__device__ __forceinline__ half8 cvt8(const float* p) {
  float4 u = *(const float4*)p;
  float4 v = *(const float4*)(p + 4);
  half8 h;
  h[0]=(_Float16)u.x; h[1]=(_Float16)u.y; h[2]=(_Float16)u.z; h[3]=(_Float16)u.w;
  h[4]=(_Float16)v.x; h[5]=(_Float16)v.y; h[6]=(_Float16)v.z; h[7]=(_Float16)v.w;
  return h;
}

__device__ __forceinline__ float sigm(float x) { return 1.f / (1.f + __expf(-x)); }

__device__ __forceinline__ unsigned wavemin64(unsigned v) {
#pragma unroll
  for (int d = 1; d < 64; d <<= 1) {
    unsigned o = (unsigned)__shfl_xor((int)v, d, 64);
    v = (o < v) ? o : v;
  }
  return v;
}

// poll a 64-word flag vector until all >= tgt (hot-spin first, then sleep)
__device__ __forceinline__ void poll1(const unsigned* f, unsigned tgt) {
  const int l = threadIdx.x & 63;
  unsigned it = 0;
  for (;;) {
    unsigned v = __hip_atomic_load(f + l, __ATOMIC_RELAXED, __HIP_MEMORY_SCOPE_AGENT);
    if (__all((int)(v >= tgt))) return;
    if (++it > 64u) __builtin_amdgcn_s_sleep(1);
    if (it > 20000000u) return;   // safety
  }
}
__device__ __forceinline__ void poll2(const unsigned* f0, const unsigned* f1, unsigned tgt) {
  const int l = threadIdx.x & 63;
  unsigned it = 0;
  for (;;) {
    unsigned v0 = __hip_atomic_load(f0 + l, __ATOMIC_RELAXED, __HIP_MEMORY_SCOPE_AGENT);
    unsigned v1 = __hip_atomic_load(f1 + l, __ATOMIC_RELAXED, __HIP_MEMORY_SCOPE_AGENT);
    if (__all((int)(v0 >= tgt && v1 >= tgt))) return;
    if (++it > 64u) __builtin_amdgcn_s_sleep(1);
    if (it > 20000000u) return;   // safety
  }
}

// one-shot UC bulk loads (sc0 sc1 -> coherence point)
__device__ __forceinline__ void uc_ld2(const unsigned* p, u32x4& a, u32x4& b) {
  asm volatile(
    "global_load_dwordx4 %0, %2, off sc0 sc1\n\t"
    "global_load_dwordx4 %1, %2, off offset:16 sc0 sc1\n\t"
    "s_waitcnt vmcnt(0)"
    : "=&v"(a), "=&v"(b) : "v"(p) : "memory");
  __builtin_amdgcn_sched_barrier(0);
}
__device__ __forceinline__ void uc_ld4(const unsigned* p, const unsigned* q,
                                       u32x4& a, u32x4& b, u32x4& c, u32x4& d) {
  asm volatile(
    "global_load_dwordx4 %0, %4, off sc0 sc1\n\t"
    "global_load_dwordx4 %1, %4, off offset:16 sc0 sc1\n\t"
    "global_load_dwordx4 %2, %5, off sc0 sc1\n\t"
    "global_load_dwordx4 %3, %5, off offset:16 sc0 sc1\n\t"
    "s_waitcnt vmcnt(0)"
    : "=&v"(a), "=&v"(b), "=&v"(c), "=&v"(d) : "v"(p), "v"(q) : "memory");
  __builtin_amdgcn_sched_barrier(0);
}

__device__ __forceinline__ void uc_st32(unsigned* p, unsigned v) {
  __hip_atomic_store(p, v, __ATOMIC_RELAXED, __HIP_MEMORY_SCOPE_AGENT);
}
__device__ __forceinline__ void uc_st64(unsigned long long* p, unsigned long long v) {
  __hip_atomic_store(p, v, __ATOMIC_RELAXED, __HIP_MEMORY_SCOPE_AGENT);
}

// ---------------- prep: build per-(sp,b) timestep lists ----------------
__global__ void prep_kernel(const int* __restrict__ spk, int* __restrict__ tlist,
                            int* __restrict__ len, int* __restrict__ meta) {
  __shared__ int slen[64];
  const int t = threadIdx.x;   // 0..63
  const int sp = t >> 3, b = t & 7;
  int cnt = 0;
  int* tl = tlist + (sp * 8 + b) * SS;
  const int4* srow = (const int4*)(spk + b * SS);
#pragma unroll 4
  for (int i = 0; i < SS / 4; ++i) {
    int4 v = srow[i];
    if (v.x == sp) tl[cnt++] = 4 * i + 0;
    if (v.y == sp) tl[cnt++] = 4 * i + 1;
    if (v.z == sp) tl[cnt++] = 4 * i + 2;
    if (v.w == sp) tl[cnt++] = 4 * i + 3;
  }
  len[t] = cnt;
  slen[t] = cnt;
  for (int i = cnt; i < SS; ++i) tl[i] = 0;  // pad so speculative reads are safe
  __syncthreads();
  if (t < 8) {
    int m = 0;
    for (int i = 0; i < 8; ++i) m = max(m, slen[t * 8 + i]);
    meta[t] = m;
  }
}

// ---------------- persistent GRU, layer-split, wave-autonomous ----------------
// 256 WGs: L = wg&1, sp = (wg>>1)&7, og = wg>>4 (16 WGs per (L,sp)).
// WG owns 32 outputs j0=og*32; wave w owns outputs j0+8w..+7 with FULL K=512
// (N-split: MFMA accumulators are final -> no cross-wave reduction).
// Per round: poll flag vector(s) -> one bulk UC load -> LDS -> ONE barrier ->
// 64 MFMA -> wave-local gate gather (LDS scratch, lgkmcnt only) -> u64 publishes
// -> per-wave vmcnt(0) drain -> per-wave flag -> shadow work (x-stage / out).
// 8-slot rings; L0 back-pressures lazily on flg1 (refreshed in shadow).
__launch_bounds__(256, 1)
__global__ void gru_main(const float* __restrict__ x,
                         const float* __restrict__ Wi, const float* __restrict__ Wh,
                         const float* __restrict__ bi, const float* __restrict__ bh,
                         const int* __restrict__ tlist, const int* __restrict__ len,
                         const int* __restrict__ meta,
                         unsigned short* __restrict__ h0ring,
                         unsigned short* __restrict__ h1ring,
                         unsigned* __restrict__ flg, float* __restrict__ out) {
  const int wg = blockIdx.x;       // 0..255
  const int L  = wg & 1;
  const int sp = (wg >> 1) & 7;
  const int og = wg >> 4;          // 0..15
  const int j0 = og * 32;
  const int tid = threadIdx.x;
  const int w  = tid >> 6;         // wave 0..3 (owns outputs j0+8w..+7)
  const int l  = tid & 63;
  const int b8 = l & 7;            // A-frag batch row (rows 8-15 duplicate)

  __shared__ __align__(16) _Float16 hstA[8][552];      // staged h0 (pitch: 16B-aligned rows)
  __shared__ __align__(16) _Float16 hstB[8][552];      // staged h1 (L1)
  __shared__ __align__(16) _Float16 xst[2][8][552];    // x f16 double-buffer (L0)
  __shared__ float sc[4][2][8][28];                    // per-wave gate scratch [w][i/h][b][24+pad]
  __shared__ __align__(8) unsigned short psc[4][64];   // per-wave publish transpose

  unsigned* flg0 = flg + (0 * 8 + sp) * 64;
  unsigned* flg1 = flg + (1 * 8 + sp) * 64;

  // ---- weight preload: full K=512 B-frags for this wave's 8 outputs (both mats) ----
  const size_t WMAT = (size_t)G3 * HH;
  const float* pWi = Wi + (size_t)(sp * 2 + L) * WMAT;
  const float* pWh = Wh + (size_t)(sp * 2 + L) * WMAT;
  const int cc0 = l & 15;
  int wrow0, wrow1;   // weight rows for tile0 (outputs jj 0-3) and tile1 (jj 4-7)
  if (cc0 < 12) {
    wrow0 = (cc0 >> 2) * HH + j0 + 8 * w + 0 + (cc0 & 3);
    wrow1 = (cc0 >> 2) * HH + j0 + 8 * w + 4 + (cc0 & 3);
  } else { wrow0 = 0; wrow1 = 0; }
  half8 bwI0[16], bwI1[16], bwH0[16], bwH1[16];
#pragma unroll
  for (int q = 0; q < 16; ++q) {
    const int k0 = (l >> 4) * 8 + q * 32;
    bwI0[q] = cvt8(pWi + (size_t)wrow0 * HH + k0);
    bwI1[q] = cvt8(pWi + (size_t)wrow1 * HH + k0);
    bwH0[q] = cvt8(pWh + (size_t)wrow0 * HH + k0);
    bwH1[q] = cvt8(pWh + (size_t)wrow1 * HH + k0);
  }

  // ---- gate-lane metadata: lane l -> (batch gb=l>>3, local output gj=l&7) ----
  const int gb = l >> 3, gj = l & 7;
  const int jmy = j0 + 8 * w + gj;
  const int lenG = len[sp * 8 + gb];
  const int* tlG = tlist + (sp * 8 + gb) * SS;
  float bgi[3], bgh[3];
#pragma unroll
  for (int g = 0; g < 3; ++g) {
    bgi[g] = bi[(sp * 2 + L) * G3 + g * HH + jmy];
    bgh[g] = bh[(sp * 2 + L) * G3 + g * HH + jmy];
  }
  // publish-lane metadata (lanes 0-15: batch l>>1, half l&1)
  const int lenP = len[sp * 8 + ((l >> 1) & 7)];

  const int R = meta[sp];
  float hprev = 0.f;
  unsigned r1min = 0;

  const int t6 = (gj >> 2) * 12, c4 = gj & 3;
  const int cc = l & 15, rg = l >> 4;
  const int stg_b = tid >> 5, stg_k = (tid & 31) * 16;

  if (L == 0) {
    // ---- prologue: stage x_0 into xst[0] ----
    {
      const int tx = tlist[(sp * 8 + stg_b) * SS + 0];
      const float* xs = x + ((size_t)stg_b * SS + tx) * HH + stg_k;
      _Float16* dst = &xst[0][stg_b][stg_k];
      *(half8*)dst = cvt8(xs);
      *(half8*)(dst + 8) = cvt8(xs + 8);
    }

    for (int r = 0; r < R; ++r) {
      // ---- poll peers (h0_{r-1} visible), one-shot bulk load, stage ----
      if (r > 0) poll1(flg0, (unsigned)r);
      {
        const unsigned* src = (const unsigned*)(h0ring +
            ((size_t)(((r - 1) & 7) * 64 + sp * 8)) * HH) + tid * 8;
        u32x4 a, b;
        uc_ld2(src, a, b);
        u32x4* d = (u32x4*)&hstA[stg_b][stg_k];
        d[0] = a; d[1] = b;
      }
      __syncthreads();   // the ONE barrier: hstA (+ xst of prev shadow) ready

      // ---- 64 MFMA: accI = Wi0*x_r, accH = Wh0*h_{r-1} (full K, final) ----
      f32x4 aI0, aI1, aH0, aH1;
#pragma unroll
      for (int e = 0; e < 4; ++e) { aI0[e]=0.f; aI1[e]=0.f; aH0[e]=0.f; aH1[e]=0.f; }
      {
        const _Float16* hrow = &hstA[b8][(l >> 4) * 8];
        const _Float16* xrow = &xst[r & 1][b8][(l >> 4) * 8];
#pragma unroll
        for (int q = 0; q < 16; ++q) {
          half8 ha = *(const half8*)(hrow + q * 32);
          half8 xa = *(const half8*)(xrow + q * 32);
          aH0 = __builtin_amdgcn_mfma_f32_16x16x32_f16(ha, bwH0[q], aH0, 0, 0, 0);
          aH1 = __builtin_amdgcn_mfma_f32_16x16x32_f16(ha, bwH1[q], aH1, 0, 0, 0);
          aI0 = __builtin_amdgcn_mfma_f32_16x16x32_f16(xa, bwI0[q], aI0, 0, 0, 0);
          aI1 = __builtin_amdgcn_mfma_f32_16x16x32_f16(xa, bwI1[q], aI1, 0, 0, 0);
        }
      }

      // ---- wave-local gate gather via LDS scratch ----
      if (cc < 12 && rg < 2) {
#pragma unroll
        for (int e = 0; e < 4; ++e) {
          sc[w][0][rg * 4 + e][cc]      = aI0[e];
          sc[w][0][rg * 4 + e][12 + cc] = aI1[e];
          sc[w][1][rg * 4 + e][cc]      = aH0[e];
          sc[w][1][rg * 4 + e][12 + cc] = aH1[e];
        }
      }
      asm volatile("s_waitcnt lgkmcnt(0)" ::: "memory");
      __builtin_amdgcn_sched_barrier(0);
      {
        float gi[3], gh[3];
#pragma unroll
        for (int g = 0; g < 3; ++g) {
          gi[g] = sc[w][0][gb][t6 + g * 4 + c4] + bgi[g];
          gh[g] = sc[w][1][gb][t6 + g * 4 + c4] + bgh[g];
        }
        const float rr_ = sigm(gi[0] + gh[0]);
        const float zz  = sigm(gi[1] + gh[1]);
        const float nn  = tanhf(gi[2] + rr_ * gh[2]);
        if (r < lenG) hprev = (1.f - zz) * nn + zz * hprev;
      }
      union { _Float16 hf; unsigned short us; } cv; cv.hf = (_Float16)hprev;
      psc[w][l] = cv.us;
      asm volatile("s_waitcnt lgkmcnt(0)" ::: "memory");
      __builtin_amdgcn_sched_barrier(0);

      // ---- back-pressure: slot r&7 must be done being read by L1 (round r-7) ----
      if (r >= 7 && (int)r1min < r - 6) {
        unsigned it = 0;
        for (;;) {
          unsigned v = __hip_atomic_load(flg1 + l, __ATOMIC_RELAXED, __HIP_MEMORY_SCOPE_AGENT);
          r1min = wavemin64(v);
          if ((int)r1min >= r - 6) break;
          __builtin_amdgcn_s_sleep(1);
          if (++it > 20000000u) break;   // safety
        }
      }

      // ---- publish h0_r (slot r&7) as u64 f16x4; drain; per-wave flag ----
      if (l < 16 && r < lenP) {
        const int pb = l >> 1;
        unsigned long long v = *(const unsigned long long*)&psc[w][(pb << 3) + ((l & 1) << 2)];
        unsigned long long* dst = (unsigned long long*)(h0ring +
            ((size_t)((r & 7) * 64 + sp * 8 + pb)) * HH + j0 + 8 * w + ((l & 1) << 2));
        uc_st64(dst, v);
      }
      asm volatile("s_waitcnt vmcnt(0)" ::: "memory");
      __builtin_amdgcn_sched_barrier(0);
      if (l == 0) uc_st32(&flg0[og * 4 + w], (unsigned)(r + 1));

      // ---- shadow: stage x_{r+1}; refresh flg1 snapshot ----
      {
        const int tx = tlist[(sp * 8 + stg_b) * SS + ((r + 1) & (SS - 1))];
        const float* xs = x + ((size_t)stg_b * SS + tx) * HH + stg_k;
        _Float16* dst = &xst[(r + 1) & 1][stg_b][stg_k];
        *(half8*)dst = cvt8(xs);
        *(half8*)(dst + 8) = cvt8(xs + 8);
      }
      {
        unsigned v = __hip_atomic_load(flg1 + l, __ATOMIC_RELAXED, __HIP_MEMORY_SCOPE_AGENT);
        r1min = wavemin64(v);
      }
    }
  } else {
    // ================= LAYER 1 (lags L0 by one round) =================
    for (int r = 0; r <= R; ++r) {
      // ---- poll (h0_{r-1} and peers' round r-1 done), bulk load both, stage ----
      if (r > 0) poll2(flg0, flg1, (unsigned)r);
      {
        const unsigned* pa = (const unsigned*)(h0ring +
            ((size_t)(((r - 1) & 7) * 64 + sp * 8)) * HH) + tid * 8;
        const unsigned* pb = (const unsigned*)(h1ring +
            ((size_t)(((r - 2) & 7) * 64 + sp * 8)) * HH) + tid * 8;
        u32x4 a, b, c, d2;
        uc_ld4(pa, pb, a, b, c, d2);
        u32x4* da = (u32x4*)&hstA[stg_b][stg_k];
        u32x4* db = (u32x4*)&hstB[stg_b][stg_k];
        da[0] = a; da[1] = b; db[0] = c; db[1] = d2;
      }
      __syncthreads();

      // ---- 64 MFMA: accI = Wi1*h0_{r-1}, accH = Wh1*h1_{r-2} ----
      f32x4 aI0, aI1, aH0, aH1;
#pragma unroll
      for (int e = 0; e < 4; ++e) { aI0[e]=0.f; aI1[e]=0.f; aH0[e]=0.f; aH1[e]=0.f; }
      {
        const _Float16* arow = &hstA[b8][(l >> 4) * 8];
        const _Float16* brow = &hstB[b8][(l >> 4) * 8];
#pragma unroll
        for (int q = 0; q < 16; ++q) {
          half8 ha = *(const half8*)(arow + q * 32);
          half8 hb = *(const half8*)(brow + q * 32);
          aI0 = __builtin_amdgcn_mfma_f32_16x16x32_f16(ha, bwI0[q], aI0, 0, 0, 0);
          aI1 = __builtin_amdgcn_mfma_f32_16x16x32_f16(ha, bwI1[q], aI1, 0, 0, 0);
          aH0 = __builtin_amdgcn_mfma_f32_16x16x32_f16(hb, bwH0[q], aH0, 0, 0, 0);
          aH1 = __builtin_amdgcn_mfma_f32_16x16x32_f16(hb, bwH1[q], aH1, 0, 0, 0);
        }
      }

      // ---- wave-local gate gather ----
      if (cc < 12 && rg < 2) {
#pragma unroll
        for (int e = 0; e < 4; ++e) {
          sc[w][0][rg * 4 + e][cc]      = aI0[e];
          sc[w][0][rg * 4 + e][12 + cc] = aI1[e];
          sc[w][1][rg * 4 + e][cc]      = aH0[e];
          sc[w][1][rg * 4 + e][12 + cc] = aH1[e];
        }
      }
      asm volatile("s_waitcnt lgkmcnt(0)" ::: "memory");
      __builtin_amdgcn_sched_barrier(0);
      const bool act = (r >= 1) && (r <= lenG);
      {
        float gi[3], gh[3];
#pragma unroll
        for (int g = 0; g < 3; ++g) {
          gi[g] = sc[w][0][gb][t6 + g * 4 + c4] + bgi[g];
          gh[g] = sc[w][1][gb][t6 + g * 4 + c4] + bgh[g];
        }
        const float rr_ = sigm(gi[0] + gh[0]);
        const float zz  = sigm(gi[1] + gh[1]);
        const float nn  = tanhf(gi[2] + rr_ * gh[2]);
        if (act) hprev = (1.f - zz) * nn + zz * hprev;
      }
      union { _Float16 hf; unsigned short us; } cv; cv.hf = (_Float16)hprev;
      psc[w][l] = cv.us;
      asm volatile("s_waitcnt lgkmcnt(0)" ::: "memory");
      __builtin_amdgcn_sched_barrier(0);

      // ---- publish h1_{r-1} (slot (r-1)&7); drain; per-wave flag ----
      if (l < 16 && r >= 1 && r <= lenP) {
        const int pb = l >> 1;
        unsigned long long v = *(const unsigned long long*)&psc[w][(pb << 3) + ((l & 1) << 2)];
        unsigned long long* dst = (unsigned long long*)(h1ring +
            ((size_t)(((r - 1) & 7) * 64 + sp * 8 + pb)) * HH + j0 + 8 * w + ((l & 1) << 2));
        uc_st64(dst, v);
      }
      asm volatile("s_waitcnt vmcnt(0)" ::: "memory");
      __builtin_amdgcn_sched_barrier(0);
      if (l == 0) uc_st32(&flg1[og * 4 + w], (unsigned)(r + 1));

      // ---- shadow: output store (plain cached; drained by next round's vmcnt) ----
      if (act) {
        const int tcur = tlG[(r - 1) & (SS - 1)];
        out[((size_t)(gb * SS + tcur)) * HH + jmy] = hprev;
      }
    }
  }
}

extern "C" void kernel_launch(void* const* d_in, const int* in_sizes, int n_in,
                              void* d_out, int out_size, void* d_ws, size_t ws_size,
                              hipStream_t stream) {
  const float* x   = (const float*)d_in[0];
  const int*   spk = (const int*)d_in[1];
  const float* Wi  = (const float*)d_in[2];
  const float* Wh  = (const float*)d_in[3];
  const float* bi  = (const float*)d_in[4];
  const float* bh  = (const float*)d_in[5];
  float* out = (float*)d_out;
  char* ws = (char*)d_ws;

  int*            tlist = (int*)(ws + OFF_TLIST);
  int*            len   = (int*)(ws + OFF_LEN);
  int*            meta  = (int*)(ws + OFF_META);
  unsigned short* h0r   = (unsigned short*)(ws + OFF_H0);
  unsigned short* h1r   = (unsigned short*)(ws + OFF_H1);
  unsigned*       flg   = (unsigned*)(ws + OFF_FLG);

  (void)in_sizes; (void)n_in; (void)out_size; (void)ws_size;

  // zero rings + flags (re-done every launch; graph-capture safe)
  hipMemsetAsync(ws + OFF_H0, 0, WS_NEED - OFF_H0, stream);
  prep_kernel<<<1, 64, 0, stream>>>(spk, tlist, len, meta);
  gru_main<<<256, 256, 0, stream>>>(x, Wi, Wh, bi, bh, tlist, len, meta,
                                    h0r, h1r, flg, out);
}

// Round 9
// 666.667 us; speedup vs baseline: 1.4311x; 1.0821x over previous
//
#include <hip/hip_runtime.h>
#include <cstdint>
#include <cstddef>

// Problem constants (fixed by the reference: B=8, S=1024, H=512, 8 speakers, 2 layers)
#define SS 1024
#define HH 512
#define G3 1536  // 3*H

typedef _Float16 half8 __attribute__((ext_vector_type(8)));
typedef float f32x4 __attribute__((ext_vector_type(4)));
typedef unsigned u32x4 __attribute__((ext_vector_type(4)));

// ---- workspace layout (bytes) ----
// Ring words: u32 = (tag<<16) | f16(h). tag = publish round + 1; memset(0)
// encodes "round -1" so round 0 consumes initial zeros with no special case.
// No flags on the critical path: consumers poll the tagged data itself.
static constexpr unsigned OFF_TLIST = 0;                 // [8][8][1024] int
static constexpr unsigned OFF_LEN   = 262144;            // [64] int
static constexpr unsigned OFF_META  = 262400;            // [8] int per-speaker max len
static constexpr unsigned OFF_H0    = 262656;            // u32[8][64][512] = 1MB
static constexpr unsigned OFF_H1    = OFF_H0 + 1048576;  // u32[8][64][512] = 1MB
static constexpr unsigned OFF_FLG   = OFF_H1 + 1048576;  // u32[8][16] L1 progress watermark
static constexpr unsigned WS_NEED   = OFF_FLG + 4096;

__device__ __forceinline__ half8 cvt8(const float* p) {
  float4 u = *(const float4*)p;
  float4 v = *(const float4*)(p + 4);
  half8 h;
  h[0]=(_Float16)u.x; h[1]=(_Float16)u.y; h[2]=(_Float16)u.z; h[3]=(_Float16)u.w;
  h[4]=(_Float16)v.x; h[5]=(_Float16)v.y; h[6]=(_Float16)v.z; h[7]=(_Float16)v.w;
  return h;
}

// strip low f16 from 8 tagged u32 words -> half8 (4x v_perm_b32)
__device__ __forceinline__ half8 pack8(u32x4 a, u32x4 b) {
  union { unsigned u[4]; half8 h; } r;
  r.u[0] = __builtin_amdgcn_perm(a[1], a[0], 0x05040100);
  r.u[1] = __builtin_amdgcn_perm(a[3], a[2], 0x05040100);
  r.u[2] = __builtin_amdgcn_perm(b[1], b[0], 0x05040100);
  r.u[3] = __builtin_amdgcn_perm(b[3], b[2], 0x05040100);
  return r.h;
}

__device__ __forceinline__ float sigm(float x) { return 1.f / (1.f + __expf(-x)); }

__device__ __forceinline__ unsigned tagbad(u32x4 v, unsigned exp) {
  return ((v[0] >> 16) ^ exp) | ((v[1] >> 16) ^ exp) |
         ((v[2] >> 16) ^ exp) | ((v[3] >> 16) ^ exp);
}

__device__ __forceinline__ unsigned wavemin64(unsigned v) {
#pragma unroll
  for (int d = 1; d < 64; d <<= 1) {
    unsigned o = (unsigned)__shfl_xor((int)v, d, 64);
    v = (o < v) ? o : v;
  }
  return v;
}

// ---- UC (sc0 sc1 -> coherence point) loads, 16B granule ----
__device__ __forceinline__ u32x4 uc_ld16(const unsigned* p) {
  u32x4 d;
  asm volatile("global_load_dwordx4 %0, %1, off sc0 sc1\n\ts_waitcnt vmcnt(0)"
               : "=v"(d) : "v"(p) : "memory");
  __builtin_amdgcn_sched_barrier(0);
  return d;
}
// 4 quads from one base (offsets 0..48), single wait
__device__ __forceinline__ void uc_ld4s(const unsigned* p,
                                        u32x4& a0, u32x4& a1, u32x4& a2, u32x4& a3) {
  asm volatile(
    "global_load_dwordx4 %0, %4, off sc0 sc1\n\t"
    "global_load_dwordx4 %1, %4, off offset:16 sc0 sc1\n\t"
    "global_load_dwordx4 %2, %4, off offset:32 sc0 sc1\n\t"
    "global_load_dwordx4 %3, %4, off offset:48 sc0 sc1\n\t"
    "s_waitcnt vmcnt(0)"
    : "=&v"(a0), "=&v"(a1), "=&v"(a2), "=&v"(a3) : "v"(p) : "memory");
  __builtin_amdgcn_sched_barrier(0);
}
// 8 quads from two bases, single wait
__device__ __forceinline__ void uc_ld8d(const unsigned* p, const unsigned* q,
                                        u32x4& a0, u32x4& a1, u32x4& a2, u32x4& a3,
                                        u32x4& b0, u32x4& b1, u32x4& b2, u32x4& b3) {
  asm volatile(
    "global_load_dwordx4 %0, %8, off sc0 sc1\n\t"
    "global_load_dwordx4 %1, %8, off offset:16 sc0 sc1\n\t"
    "global_load_dwordx4 %2, %8, off offset:32 sc0 sc1\n\t"
    "global_load_dwordx4 %3, %8, off offset:48 sc0 sc1\n\t"
    "global_load_dwordx4 %4, %9, off sc0 sc1\n\t"
    "global_load_dwordx4 %5, %9, off offset:16 sc0 sc1\n\t"
    "global_load_dwordx4 %6, %9, off offset:32 sc0 sc1\n\t"
    "global_load_dwordx4 %7, %9, off offset:48 sc0 sc1\n\t"
    "s_waitcnt vmcnt(0)"
    : "=&v"(a0), "=&v"(a1), "=&v"(a2), "=&v"(a3),
      "=&v"(b0), "=&v"(b1), "=&v"(b2), "=&v"(b3)
    : "v"(p), "v"(q) : "memory");
  __builtin_amdgcn_sched_barrier(0);
}

__device__ __forceinline__ void uc_st32(unsigned* p, unsigned v) {
  __hip_atomic_store(p, v, __ATOMIC_RELAXED, __HIP_MEMORY_SCOPE_AGENT);
}
__device__ __forceinline__ void uc_st64(unsigned long long* p, unsigned long long v) {
  __hip_atomic_store(p, v, __ATOMIC_RELAXED, __HIP_MEMORY_SCOPE_AGENT);
}

// ---------------- prep: build per-(sp,b) timestep lists ----------------
__global__ void prep_kernel(const int* __restrict__ spk, int* __restrict__ tlist,
                            int* __restrict__ len, int* __restrict__ meta) {
  __shared__ int slen[64];
  const int t = threadIdx.x;   // 0..63
  const int sp = t >> 3, b = t & 7;
  int cnt = 0;
  int* tl = tlist + (sp * 8 + b) * SS;
  const int4* srow = (const int4*)(spk + b * SS);
#pragma unroll 4
  for (int i = 0; i < SS / 4; ++i) {
    int4 v = srow[i];
    if (v.x == sp) tl[cnt++] = 4 * i + 0;
    if (v.y == sp) tl[cnt++] = 4 * i + 1;
    if (v.z == sp) tl[cnt++] = 4 * i + 2;
    if (v.w == sp) tl[cnt++] = 4 * i + 3;
  }
  len[t] = cnt;
  slen[t] = cnt;
  for (int i = cnt; i < SS; ++i) tl[i] = 0;  // pad so speculative reads are safe
  __syncthreads();
  if (t < 8) {
    int m = 0;
    for (int i = 0; i < 8; ++i) m = max(m, slen[t * 8 + i]);
    meta[t] = m;
  }
}

// ---------------- persistent GRU, layer-split, tag-in-data ----------------
// 256 WGs: L = wg&1, sp = (wg>>1)&7, og = wg>>4. WG owns 32 outputs of one layer;
// wave w owns outputs j0+8w..+7 with FULL K=512 (final accumulators, no cross-
// wave reduction). Sync: ring words carry their round tag; consumers poll the
// tagged data with 16B dwordx4 loads, retrying only stale quads. Producers
// publish and continue (no drain, no flag). 8-slot rings; slot reuse is safe
// transitively among tag-polling peers; L0 checks L1's staging watermark
// (posted off-path) before overwriting a slot L1 still needs.
__launch_bounds__(256, 1)
__global__ void gru_main(const float* __restrict__ x,
                         const float* __restrict__ Wi, const float* __restrict__ Wh,
                         const float* __restrict__ bi, const float* __restrict__ bh,
                         const int* __restrict__ tlist, const int* __restrict__ len,
                         const int* __restrict__ meta,
                         unsigned* __restrict__ h0ring, unsigned* __restrict__ h1ring,
                         unsigned* __restrict__ flg, float* __restrict__ out) {
  const int wg = blockIdx.x;       // 0..255
  const int L  = wg & 1;
  const int sp = (wg >> 1) & 7;
  const int og = wg >> 4;          // 0..15
  const int j0 = og * 32;
  const int tid = threadIdx.x;
  const int w  = tid >> 6;         // wave 0..3 (owns outputs j0+8w..+7)
  const int l  = tid & 63;
  const int b8 = l & 7;            // A-frag batch row (rows 8-15 duplicate)

  __shared__ __align__(16) _Float16 hstA[8][552];      // staged h0 (stripped f16)
  __shared__ __align__(16) _Float16 hstB[8][552];      // staged h1 (L1)
  __shared__ __align__(16) _Float16 xst[2][8][552];    // x f16 double-buffer (L0)
  __shared__ float sc[4][2][8][28];                    // per-wave gate scratch
  __shared__ __align__(8) unsigned short psc[4][64];   // per-wave publish transpose

  unsigned* flg1 = flg + sp * 16;                      // L1 staging watermark [16]

  // ---- weight preload: full K=512 B-frags for this wave's 8 outputs (both mats) ----
  const size_t WMAT = (size_t)G3 * HH;
  const float* pWi = Wi + (size_t)(sp * 2 + L) * WMAT;
  const float* pWh = Wh + (size_t)(sp * 2 + L) * WMAT;
  const int cc0 = l & 15;
  int wrow0, wrow1;   // weight rows for tile0 (outputs 0-3) and tile1 (outputs 4-7)
  if (cc0 < 12) {
    wrow0 = (cc0 >> 2) * HH + j0 + 8 * w + 0 + (cc0 & 3);
    wrow1 = (cc0 >> 2) * HH + j0 + 8 * w + 4 + (cc0 & 3);
  } else { wrow0 = 0; wrow1 = 0; }
  half8 bwI0[16], bwI1[16], bwH0[16], bwH1[16];
#pragma unroll
  for (int q = 0; q < 16; ++q) {
    const int k0 = (l >> 4) * 8 + q * 32;
    bwI0[q] = cvt8(pWi + (size_t)wrow0 * HH + k0);
    bwI1[q] = cvt8(pWi + (size_t)wrow1 * HH + k0);
    bwH0[q] = cvt8(pWh + (size_t)wrow0 * HH + k0);
    bwH1[q] = cvt8(pWh + (size_t)wrow1 * HH + k0);
  }

  // ---- gate-lane metadata: lane l -> (batch gb=l>>3, local output gj=l&7) ----
  const int gb = l >> 3, gj = l & 7;
  const int jmy = j0 + 8 * w + gj;
  const int lenG = len[sp * 8 + gb];
  const int* tlG = tlist + (sp * 8 + gb) * SS;
  float bgi[3], bgh[3];
#pragma unroll
  for (int g = 0; g < 3; ++g) {
    bgi[g] = bi[(sp * 2 + L) * G3 + g * HH + jmy];
    bgh[g] = bh[(sp * 2 + L) * G3 + g * HH + jmy];
  }

  const int R = meta[sp];
  float hprev = 0.f;
  unsigned r1min = 0;

  const int t6 = (gj >> 2) * 12, c4 = gj & 3;
  const int cc = l & 15, rg = l >> 4;
  const int stg_b = tid >> 5;            // staged chain
  const int stg_k = (tid & 31) * 16;     // staged f16 col base (16 cols/thread)

  if (L == 0) {
    // ================= LAYER 0 (critical self-loop) =================
    // prologue: stage x_0 into xst[0]
    {
      const int tx = tlist[(sp * 8 + stg_b) * SS + 0];
      const float* xs = x + ((size_t)stg_b * SS + tx) * HH + stg_k;
      _Float16* dst = &xst[0][stg_b][stg_k];
      *(half8*)dst = cvt8(xs);
      *(half8*)(dst + 8) = cvt8(xs + 8);
    }

    for (int r = 0; r < R; ++r) {
      // ---- poll tagged h0 slot (r-1)&7 (expect tag r); stage stripped f16 ----
      {
        const unsigned exp = (unsigned)r;
        const unsigned* src = h0ring +
            ((size_t)(((r - 1) & 7) * 64 + sp * 8)) * HH + tid * 16;
        u32x4 q0, q1, q2, q3;
        uc_ld4s(src, q0, q1, q2, q3);
        unsigned it = 0;
        for (;;) {
          const unsigned d0 = tagbad(q0, exp), d1 = tagbad(q1, exp);
          const unsigned d2 = tagbad(q2, exp), d3 = tagbad(q3, exp);
          if (!(d0 | d1 | d2 | d3)) break;
          if (++it > 16u) __builtin_amdgcn_s_sleep(1);
          if (it > 5000000u) break;   // safety
          if (d0) q0 = uc_ld16(src + 0);
          if (d1) q1 = uc_ld16(src + 4);
          if (d2) q2 = uc_ld16(src + 8);
          if (d3) q3 = uc_ld16(src + 12);
        }
        *(half8*)&hstA[stg_b][stg_k]     = pack8(q0, q1);
        *(half8*)&hstA[stg_b][stg_k + 8] = pack8(q2, q3);
      }
      __syncthreads();   // hstA + xst[r&1] (prev shadow) ready

      // ---- 64 MFMA: accI = Wi0*x_r, accH = Wh0*h_{r-1} (full K, final) ----
      f32x4 aI0, aI1, aH0, aH1;
#pragma unroll
      for (int e = 0; e < 4; ++e) { aI0[e]=0.f; aI1[e]=0.f; aH0[e]=0.f; aH1[e]=0.f; }
      {
        const _Float16* hrow = &hstA[b8][(l >> 4) * 8];
        const _Float16* xrow = &xst[r & 1][b8][(l >> 4) * 8];
#pragma unroll
        for (int q = 0; q < 16; ++q) {
          half8 ha = *(const half8*)(hrow + q * 32);
          half8 xa = *(const half8*)(xrow + q * 32);
          aH0 = __builtin_amdgcn_mfma_f32_16x16x32_f16(ha, bwH0[q], aH0, 0, 0, 0);
          aH1 = __builtin_amdgcn_mfma_f32_16x16x32_f16(ha, bwH1[q], aH1, 0, 0, 0);
          aI0 = __builtin_amdgcn_mfma_f32_16x16x32_f16(xa, bwI0[q], aI0, 0, 0, 0);
          aI1 = __builtin_amdgcn_mfma_f32_16x16x32_f16(xa, bwI1[q], aI1, 0, 0, 0);
        }
      }

      // ---- wave-local gate gather via LDS scratch ----
      if (cc < 12 && rg < 2) {
#pragma unroll
        for (int e = 0; e < 4; ++e) {
          sc[w][0][rg * 4 + e][cc]      = aI0[e];
          sc[w][0][rg * 4 + e][12 + cc] = aI1[e];
          sc[w][1][rg * 4 + e][cc]      = aH0[e];
          sc[w][1][rg * 4 + e][12 + cc] = aH1[e];
        }
      }
      asm volatile("s_waitcnt lgkmcnt(0)" ::: "memory");
      __builtin_amdgcn_sched_barrier(0);
      {
        float gi[3], gh[3];
#pragma unroll
        for (int g = 0; g < 3; ++g) {
          gi[g] = sc[w][0][gb][t6 + g * 4 + c4] + bgi[g];
          gh[g] = sc[w][1][gb][t6 + g * 4 + c4] + bgh[g];
        }
        const float rr_ = sigm(gi[0] + gh[0]);
        const float zz  = sigm(gi[1] + gh[1]);
        const float nn  = tanhf(gi[2] + rr_ * gh[2]);
        if (r < lenG) hprev = (1.f - zz) * nn + zz * hprev;
      }
      union { _Float16 hf; unsigned short us; } cv; cv.hf = (_Float16)hprev;
      psc[w][l] = cv.us;
      asm volatile("s_waitcnt lgkmcnt(0)" ::: "memory");
      __builtin_amdgcn_sched_barrier(0);

      // ---- back-pressure: L1 must have staged round r-7 before slot r&7
      //      (holding h0_{r-8}) is overwritten; watermark >= r-6 <=> staged r-7 ----
      if (r >= 7 && (int)r1min < r - 6) {
        unsigned it = 0;
        for (;;) {
          unsigned v = __hip_atomic_load(flg1 + (l & 15), __ATOMIC_RELAXED,
                                         __HIP_MEMORY_SCOPE_AGENT);
          r1min = wavemin64(v);
          if ((int)r1min >= r - 6) break;
          __builtin_amdgcn_s_sleep(1);
          if (++it > 5000000u) break;   // safety
        }
      }

      // ---- publish h0_r (slot r&7) as tagged u64 pairs; NO drain, NO flag ----
      {
        const unsigned tagw = ((unsigned)(r + 1)) << 16;
        if (l < 32) {
          const int pb = l >> 2, pr = l & 3;
          const unsigned v = *(const unsigned*)&psc[w][pb * 8 + 2 * pr];
          const unsigned long long d =
              (unsigned long long)(tagw | (v & 0xffffu)) |
              ((unsigned long long)(tagw | (v >> 16)) << 32);
          unsigned long long* dst = (unsigned long long*)(h0ring +
              ((size_t)((r & 7) * 64 + sp * 8 + pb)) * HH + j0 + 8 * w + 2 * pr);
          uc_st64(dst, d);
        }
      }

      // ---- shadow: stage x_{r+1}; refresh L1 watermark snapshot ----
      {
        const int tx = tlist[(sp * 8 + stg_b) * SS + ((r + 1) & (SS - 1))];
        const float* xs = x + ((size_t)stg_b * SS + tx) * HH + stg_k;
        _Float16* dst = &xst[(r + 1) & 1][stg_b][stg_k];
        *(half8*)dst = cvt8(xs);
        *(half8*)(dst + 8) = cvt8(xs + 8);
      }
      {
        unsigned v = __hip_atomic_load(flg1 + (l & 15), __ATOMIC_RELAXED,
                                       __HIP_MEMORY_SCOPE_AGENT);
        r1min = wavemin64(v);
      }
    }
  } else {
    // ================= LAYER 1 (lags L0 by one round) =================
    for (int r = 0; r <= R; ++r) {
      // ---- poll tagged h0 slot (r-1)&7 + h1 slot (r-2)&7 (both expect tag r) ----
      {
        const unsigned exp = (unsigned)r;
        const unsigned* pa = h0ring +
            ((size_t)(((r - 1) & 7) * 64 + sp * 8)) * HH + tid * 16;
        const unsigned* pb = h1ring +
            ((size_t)(((r - 2) & 7) * 64 + sp * 8)) * HH + tid * 16;
        u32x4 a0, a1, a2, a3, c0, c1, c2, c3;
        uc_ld8d(pa, pb, a0, a1, a2, a3, c0, c1, c2, c3);
        unsigned it = 0;
        for (;;) {
          const unsigned d0 = tagbad(a0, exp), d1 = tagbad(a1, exp);
          const unsigned d2 = tagbad(a2, exp), d3 = tagbad(a3, exp);
          const unsigned e0 = tagbad(c0, exp), e1 = tagbad(c1, exp);
          const unsigned e2 = tagbad(c2, exp), e3 = tagbad(c3, exp);
          if (!(d0 | d1 | d2 | d3 | e0 | e1 | e2 | e3)) break;
          if (++it > 16u) __builtin_amdgcn_s_sleep(1);
          if (it > 5000000u) break;   // safety
          if (d0) a0 = uc_ld16(pa + 0);
          if (d1) a1 = uc_ld16(pa + 4);
          if (d2) a2 = uc_ld16(pa + 8);
          if (d3) a3 = uc_ld16(pa + 12);
          if (e0) c0 = uc_ld16(pb + 0);
          if (e1) c1 = uc_ld16(pb + 4);
          if (e2) c2 = uc_ld16(pb + 8);
          if (e3) c3 = uc_ld16(pb + 12);
        }
        *(half8*)&hstA[stg_b][stg_k]     = pack8(a0, a1);
        *(half8*)&hstA[stg_b][stg_k + 8] = pack8(a2, a3);
        *(half8*)&hstB[stg_b][stg_k]     = pack8(c0, c1);
        *(half8*)&hstB[stg_b][stg_k + 8] = pack8(c2, c3);
      }
      __syncthreads();
      // staging watermark for L0's slot reuse (off critical path, no drain needed:
      // the staged values are already in registers/LDS)
      if (tid == 0) uc_st32(&flg1[og], (unsigned)(r + 1));

      // ---- 64 MFMA: accI = Wi1*h0_{r-1}, accH = Wh1*h1_{r-2} ----
      f32x4 aI0, aI1, aH0, aH1;
#pragma unroll
      for (int e = 0; e < 4; ++e) { aI0[e]=0.f; aI1[e]=0.f; aH0[e]=0.f; aH1[e]=0.f; }
      {
        const _Float16* arow = &hstA[b8][(l >> 4) * 8];
        const _Float16* brow = &hstB[b8][(l >> 4) * 8];
#pragma unroll
        for (int q = 0; q < 16; ++q) {
          half8 ha = *(const half8*)(arow + q * 32);
          half8 hb = *(const half8*)(brow + q * 32);
          aI0 = __builtin_amdgcn_mfma_f32_16x16x32_f16(ha, bwI0[q], aI0, 0, 0, 0);
          aI1 = __builtin_amdgcn_mfma_f32_16x16x32_f16(ha, bwI1[q], aI1, 0, 0, 0);
          aH0 = __builtin_amdgcn_mfma_f32_16x16x32_f16(hb, bwH0[q], aH0, 0, 0, 0);
          aH1 = __builtin_amdgcn_mfma_f32_16x16x32_f16(hb, bwH1[q], aH1, 0, 0, 0);
        }
      }

      // ---- wave-local gate gather ----
      if (cc < 12 && rg < 2) {
#pragma unroll
        for (int e = 0; e < 4; ++e) {
          sc[w][0][rg * 4 + e][cc]      = aI0[e];
          sc[w][0][rg * 4 + e][12 + cc] = aI1[e];
          sc[w][1][rg * 4 + e][cc]      = aH0[e];
          sc[w][1][rg * 4 + e][12 + cc] = aH1[e];
        }
      }
      asm volatile("s_waitcnt lgkmcnt(0)" ::: "memory");
      __builtin_amdgcn_sched_barrier(0);
      const bool act = (r >= 1) && (r <= lenG);
      {
        float gi[3], gh[3];
#pragma unroll
        for (int g = 0; g < 3; ++g) {
          gi[g] = sc[w][0][gb][t6 + g * 4 + c4] + bgi[g];
          gh[g] = sc[w][1][gb][t6 + g * 4 + c4] + bgh[g];
        }
        const float rr_ = sigm(gi[0] + gh[0]);
        const float zz  = sigm(gi[1] + gh[1]);
        const float nn  = tanhf(gi[2] + rr_ * gh[2]);
        if (act) hprev = (1.f - zz) * nn + zz * hprev;
      }
      union { _Float16 hf; unsigned short us; } cv; cv.hf = (_Float16)hprev;
      psc[w][l] = cv.us;
      asm volatile("s_waitcnt lgkmcnt(0)" ::: "memory");
      __builtin_amdgcn_sched_barrier(0);

      // ---- publish h1_{r-1} (slot (r-1)&7) as tagged u64 pairs ----
      {
        const unsigned tagw = ((unsigned)(r + 1)) << 16;
        if (l < 32) {
          const int pb = l >> 2, pr = l & 3;
          const unsigned v = *(const unsigned*)&psc[w][pb * 8 + 2 * pr];
          const unsigned long long d =
              (unsigned long long)(tagw | (v & 0xffffu)) |
              ((unsigned long long)(tagw | (v >> 16)) << 32);
          unsigned long long* dst = (unsigned long long*)(h1ring +
              ((size_t)(((r - 1) & 7) * 64 + sp * 8 + pb)) * HH + j0 + 8 * w + 2 * pr);
          uc_st64(dst, d);
        }
      }

      // ---- shadow: output store (plain cached) ----
      if (act) {
        const int tcur = tlG[(r - 1) & (SS - 1)];
        out[((size_t)(gb * SS + tcur)) * HH + jmy] = hprev;
      }
    }
  }
}

extern "C" void kernel_launch(void* const* d_in, const int* in_sizes, int n_in,
                              void* d_out, int out_size, void* d_ws, size_t ws_size,
                              hipStream_t stream) {
  const float* x   = (const float*)d_in[0];
  const int*   spk = (const int*)d_in[1];
  const float* Wi  = (const float*)d_in[2];
  const float* Wh  = (const float*)d_in[3];
  const float* bi  = (const float*)d_in[4];
  const float* bh  = (const float*)d_in[5];
  float* out = (float*)d_out;
  char* ws = (char*)d_ws;

  int*      tlist = (int*)(ws + OFF_TLIST);
  int*      len   = (int*)(ws + OFF_LEN);
  int*      meta  = (int*)(ws + OFF_META);
  unsigned* h0r   = (unsigned*)(ws + OFF_H0);
  unsigned* h1r   = (unsigned*)(ws + OFF_H1);
  unsigned* flg   = (unsigned*)(ws + OFF_FLG);

  (void)in_sizes; (void)n_in; (void)out_size; (void)ws_size;

  // zero rings (tags -> "round -1") + watermark; re-done every launch
  hipMemsetAsync(ws + OFF_H0, 0, WS_NEED - OFF_H0, stream);
  prep_kernel<<<1, 64, 0, stream>>>(spk, tlist, len, meta);
  gru_main<<<256, 256, 0, stream>>>(x, Wi, Wh, bi, bh, tlist, len, meta,
                                    h0r, h1r, flg, out);
}